// Round 6
// baseline (886.353 us; speedup 1.0000x reference)
//
#include <hip/hip_runtime.h>
#include <hip/hip_fp16.h>

#define NLV 16
#define TBL (1u << 19)
#define TMASK (TBL - 1u)
#define P1 2654435761u
#define P2 805459861u

typedef float vf2 __attribute__((ext_vector_type(2)));
typedef float vf4 __attribute__((ext_vector_type(4)));
typedef unsigned vu2 __attribute__((ext_vector_type(2)));
typedef unsigned vu4 __attribute__((ext_vector_type(4)));

__device__ __forceinline__ vf2 h2_to_f2(unsigned bits) {
    union { unsigned u; __half2 h; } c; c.u = bits;
    float2 f = __half22float2(c.h);
    vf2 r; r.x = f.x; r.y = f.y; return r;
}
__device__ __forceinline__ unsigned f2_to_h2(float a, float b) {
    union { __half2 h; unsigned u; } c; c.h = __floats2half2_rn(a, b);
    return c.u;
}

// ---------------------------------------------------------------------------
// Pre-pass: convert f32 tables ([L][T][2] floats) to packed fp16 (u32/entry).
// 2 entries per thread: 16B read, 8B write.
// ---------------------------------------------------------------------------
__global__ __launch_bounds__(256) void convert_tables(
    const float* __restrict__ tables, unsigned* __restrict__ htab, int total)
{
    int i = blockIdx.x * 256 + threadIdx.x;
    int e0 = i * 2;
    if (e0 >= total) return;
    vf4 v = *(const vf4*)(tables + (size_t)e0 * 2);
    vu2 o; o.x = f2_to_h2(v.x, v.y); o.y = f2_to_h2(v.z, v.w);
    *(vu2*)(htab + e0) = o;
}

// ---------------------------------------------------------------------------
// Pass 1: level-major gather, fp16 table, x-pair fused loads.
// prime_x == 1 => h(x+1) = h(x) ^ 1 for even x: both x-neighbor corners live
// in the aligned 2-slot pair -> one 8B load serves 2 corners.
// Even cx: 4 requests/level; odd cx: 8 (exec-masked extra pair). avg 6 (was 8).
// Output: u32 (2xfp16) per point per level, [L][n], coalesced.
// ---------------------------------------------------------------------------
__global__ __launch_bounds__(256) void ngp_gather_h(
    const float* __restrict__ xyz,
    const unsigned* __restrict__ htab,
    const int* __restrict__ resolutions,
    unsigned* __restrict__ wsout,
    int n, int nbPerLevel)
{
    int L = blockIdx.x / nbPerLevel;
    int chunk = blockIdx.x % nbPerLevel;
    int p0 = chunk * 512 + (int)threadIdx.x;

    float res = (float)resolutions[L];
    const unsigned* __restrict__ tab = htab + (size_t)L * TBL;
    unsigned* __restrict__ wl = wsout + (size_t)L * n;

#pragma unroll
    for (int q = 0; q < 2; ++q) {
        int p = p0 + q * 256;
        if (p >= n) continue;

        float x = xyz[(size_t)p * 3 + 0];
        float y = xyz[(size_t)p * 3 + 1];
        float z = xyz[(size_t)p * 3 + 2];
        float ux = x * 0.5f + 0.5f;
        float uy = y * 0.5f + 0.5f;
        float uz = z * 0.5f + 0.5f;
        float px = ux * res, py = uy * res, pz = uz * res;
        float fx = floorf(px), fy = floorf(py), fz = floorf(pz);
        float wx = px - fx, wy = py - fy, wz = pz - fz;
        unsigned cx = (unsigned)fx, cy = (unsigned)fy, cz = (unsigned)fz;
        float vx = 1.0f - wx, vy = 1.0f - wy, vz = 1.0f - wz;

        unsigned e = cx & ~1u;
        unsigned odd = cx & 1u;
        unsigned hy0 = cy * P1, hy1 = hy0 + P1;
        unsigned hz0 = cz * P2, hz1 = hz0 + P2;

        unsigned R[4];
        R[0] = hy0 ^ hz0; R[1] = hy1 ^ hz0;
        R[2] = hy0 ^ hz1; R[3] = hy1 ^ hz1;
        float wyz[4];
        wyz[0] = vy * vz; wyz[1] = wy * vz;
        wyz[2] = vy * wz; wyz[3] = wy * wz;

        // pair A: x in {e, e+1}; slot of x=e is idxA, x=e+1 at idxA^1.
        vu2 dA[4]; unsigned selA[4];
#pragma unroll
        for (int j = 0; j < 4; ++j) {
            unsigned idx = (e ^ R[j]) & TMASK;
            selA[j] = idx & 1u;
            dA[j] = *(const vu2*)(tab + (idx & ~1u));
        }
        // pair B: x in {e+2, e+3}; only needed when cx odd (x1 = e+2).
        vu2 dB[4] = {}; unsigned selB[4] = {};
        if (odd) {
#pragma unroll
            for (int j = 0; j < 4; ++j) {
                unsigned idx = ((e + 2u) ^ R[j]) & TMASK;
                selB[j] = idx & 1u;
                dB[j] = *(const vu2*)(tab + (idx & ~1u));
            }
        }

        float a0 = 0.0f, a1 = 0.0f;
#pragma unroll
        for (int j = 0; j < 4; ++j) {
            unsigned s0 = selA[j] ^ odd;                 // half holding x=cx
            unsigned b0 = s0 ? dA[j].y : dA[j].x;
            unsigned fromA = selA[j] ? dA[j].x : dA[j].y; // half x=e+1
            unsigned fromB = selB[j] ? dB[j].y : dB[j].x; // half x=e+2
            unsigned b1 = odd ? fromB : fromA;            // x = cx+1
            vf2 f0 = h2_to_f2(b0);
            vf2 f1 = h2_to_f2(b1);
            float W0 = wyz[j] * vx;
            float W1 = wyz[j] * wx;
            a0 += f0.x * W0; a0 += f1.x * W1;
            a1 += f0.y * W0; a1 += f1.y * W1;
        }
        wl[p] = f2_to_h2(a0, a1);
    }
}

// ---------------------------------------------------------------------------
// Pass 2: streaming transpose fp16 ws -> f32 output rows. 4 points/thread:
// 16 x 16B coalesced reads, 4 x 128B row writes.
// ---------------------------------------------------------------------------
__global__ __launch_bounds__(256) void ngp_transpose_h(
    const unsigned* __restrict__ ws,
    float* __restrict__ out, int n)
{
    int t = blockIdx.x * 256 + threadIdx.x;
    int p = t * 4;
    if (p >= n) return;

    if (p + 3 < n && (n & 3) == 0) {
        vu4 m[NLV];
#pragma unroll
        for (int L = 0; L < NLV; ++L)
            m[L] = *(const vu4*)(ws + (size_t)L * n + p);
#pragma unroll
        for (int pt = 0; pt < 4; ++pt) {
            vf4* o = (vf4*)(out + (size_t)(p + pt) * (NLV * 2));
#pragma unroll
            for (int i = 0; i < 8; ++i) {
                unsigned ba = pt == 0 ? m[2 * i].x : pt == 1 ? m[2 * i].y
                             : pt == 2 ? m[2 * i].z : m[2 * i].w;
                unsigned bb = pt == 0 ? m[2 * i + 1].x : pt == 1 ? m[2 * i + 1].y
                             : pt == 2 ? m[2 * i + 1].z : m[2 * i + 1].w;
                vf2 ga = h2_to_f2(ba), gb = h2_to_f2(bb);
                vf4 r; r.x = ga.x; r.y = ga.y; r.z = gb.x; r.w = gb.y;
                o[i] = r;
            }
        }
    } else {
        for (int pt = 0; pt < 4 && p + pt < n; ++pt) {
            vf4* o = (vf4*)(out + (size_t)(p + pt) * (NLV * 2));
#pragma unroll
            for (int i = 0; i < 8; ++i) {
                vf2 ga = h2_to_f2(ws[(size_t)(2 * i) * n + p + pt]);
                vf2 gb = h2_to_f2(ws[(size_t)(2 * i + 1) * n + p + pt]);
                vf4 r; r.x = ga.x; r.y = ga.y; r.z = gb.x; r.w = gb.y;
                o[i] = r;
            }
        }
    }
}

// ---------------------------------------------------------------------------
// Fallback: single-pass point-major f32 kernel (ws too small).
// ---------------------------------------------------------------------------
__global__ __launch_bounds__(256) void ngp_encode_kernel(
    const float* __restrict__ xyz,
    const float* __restrict__ tables,
    const int* __restrict__ resolutions,
    float* __restrict__ out,
    int n)
{
    int p = blockIdx.x * blockDim.x + threadIdx.x;
    if (p >= n) return;

    float x = xyz[(size_t)p * 3 + 0];
    float y = xyz[(size_t)p * 3 + 1];
    float z = xyz[(size_t)p * 3 + 2];
    float ux = x * 0.5f + 0.5f;
    float uy = y * 0.5f + 0.5f;
    float uz = z * 0.5f + 0.5f;

    float acc[NLV * 2];

#pragma unroll
    for (int L = 0; L < NLV; ++L) {
        float res = (float)resolutions[L];
        float px = ux * res, py = uy * res, pz = uz * res;
        float fx = floorf(px), fy = floorf(py), fz = floorf(pz);
        float wx = px - fx, wy = py - fy, wz = pz - fz;
        unsigned cx = (unsigned)fx, cy = (unsigned)fy, cz = (unsigned)fz;
        unsigned hx0 = cx, hx1 = cx + 1u;
        unsigned hy0 = cy * P1, hy1 = hy0 + P1;
        unsigned hz0 = cz * P2, hz1 = hz0 + P2;
        const vf2* __restrict__ tab = (const vf2*)tables + (size_t)L * TBL;
        float vx = 1.0f - wx, vy = 1.0f - wy, vz = 1.0f - wz;
        float a0 = 0.0f, a1 = 0.0f;
#pragma unroll
        for (int c = 0; c < 8; ++c) {
            unsigned h = ((c & 1) ? hx1 : hx0) ^
                         ((c & 2) ? hy1 : hy0) ^
                         ((c & 4) ? hz1 : hz0);
            vf2 f = tab[h & TMASK];
            float w = ((c & 1) ? wx : vx) *
                      ((c & 2) ? wy : vy) *
                      ((c & 4) ? wz : vz);
            a0 += f.x * w;
            a1 += f.y * w;
        }
        acc[L * 2 + 0] = a0;
        acc[L * 2 + 1] = a1;
    }

    vf4* o = (vf4*)(out + (size_t)p * (NLV * 2));
#pragma unroll
    for (int i = 0; i < 8; ++i) {
        vf4 r; r.x = acc[i * 4 + 0]; r.y = acc[i * 4 + 1];
        r.z = acc[i * 4 + 2]; r.w = acc[i * 4 + 3];
        o[i] = r;
    }
}

extern "C" void kernel_launch(void* const* d_in, const int* in_sizes, int n_in,
                              void* d_out, int out_size, void* d_ws, size_t ws_size,
                              hipStream_t stream) {
    const float* xyz = (const float*)d_in[0];
    const float* tables = (const float*)d_in[1];
    const int* resolutions = (const int*)d_in[2];
    float* out = (float*)d_out;

    int n = in_sizes[0] / 3;
    const int totalEntries = NLV * (int)TBL;               // 8.39M
    const size_t tabBytes = (size_t)totalEntries * 4;      // 33.5 MB
    const size_t wsoutBytes = (size_t)NLV * (size_t)n * 4; // 134 MB @ n=2^21

    if (ws_size >= tabBytes + wsoutBytes) {
        unsigned* htab = (unsigned*)d_ws;
        unsigned* wsout = (unsigned*)((char*)d_ws + tabBytes);

        int gridC = (totalEntries / 2 + 255) / 256;
        hipLaunchKernelGGL(convert_tables, dim3(gridC), dim3(256), 0, stream,
                           tables, htab, totalEntries);

        int nbPerLevel = (n + 511) / 512;
        int grid1 = NLV * nbPerLevel;
        hipLaunchKernelGGL(ngp_gather_h, dim3(grid1), dim3(256), 0, stream,
                           xyz, htab, resolutions, wsout, n, nbPerLevel);

        int grid2 = ((n + 3) / 4 + 255) / 256;
        hipLaunchKernelGGL(ngp_transpose_h, dim3(grid2), dim3(256), 0, stream,
                           wsout, out, n);
    } else {
        int grid = (n + 255) / 256;
        hipLaunchKernelGGL(ngp_encode_kernel, dim3(grid), dim3(256), 0, stream,
                           xyz, tables, resolutions, out, n);
    }
}